// Round 5
// baseline (882.388 us; speedup 1.0000x reference)
//
#include <hip/hip_runtime.h>
#include <hip/hip_bf16.h>
#include <math.h>

#define NRES 768
#define C1 384
#define C2 128
#define NH 12
#define HB 6   // heads per k2 block

// ws float offsets (UNCHANGED verified layout — no growth)
#define OFF_QS   0          // 768*192
#define OFF_KS   147456
#define OFF_VS   294912
#define OFF_QPT  442368     // 768*144
#define OFF_KPT  552960
#define OFF_VPT  663552     // 768*288
#define OFF_FA   884736     // 768*2112
#define OFF_RAW  OFF_FA     // raw projections aliased into fa region

__device__ __forceinline__ float dot4(float4 a, float4 b) {
    return fmaf(a.x, b.x, fmaf(a.y, b.y, fmaf(a.z, b.z, a.w * b.w)));
}

static constexpr float SCALAR_W = 0.14433756729740643f; // sqrt(1/48)
static constexpr float POINT_W  = 0.13608276348795434f; // sqrt(1/54)
static constexpr float W2D_W    = 0.57735026918962576f; // sqrt(1/3)

__device__ __forceinline__ void wsel(int o,
    const float* w_qs, const float* b_qs, const float* w_kvs, const float* b_kvs,
    const float* w_qp, const float* b_qp, const float* w_kvp, const float* b_kvp,
    const float** row, float* bias)
{
    if (o < 192)      { *row = w_qs  + (size_t)o * C1;         *bias = b_qs[o]; }
    else if (o < 576) { *row = w_kvs + (size_t)(o - 192) * C1; *bias = b_kvs[o - 192]; }
    else if (o < 720) { *row = w_qp  + (size_t)(o - 576) * C1; *bias = b_qp[o - 576]; }
    else              { *row = w_kvp + (size_t)(o - 720) * C1; *bias = b_kvp[o - 720]; }
}

// ---------------------------------------------------------------------------
// K1: raw = in1d @ W_all.T + b_all  (768 x 1152, K=384), tiled GEMM.
// ---------------------------------------------------------------------------
__global__ __launch_bounds__(256) void k1_gemm(
    const float* __restrict__ in1d,
    const float* __restrict__ w_qs, const float* __restrict__ b_qs,
    const float* __restrict__ w_kvs, const float* __restrict__ b_kvs,
    const float* __restrict__ w_qp, const float* __restrict__ b_qp,
    const float* __restrict__ w_kvp, const float* __restrict__ b_kvp,
    float* __restrict__ ws)
{
    __shared__ __align__(16) float ASt[32][68];
    __shared__ __align__(16) float WSt[32][68];
    const int t = threadIdx.x;
    const int n0 = blockIdx.x * 64;
    const int o0 = blockIdx.y * 64;
    const int tx = t & 15, ty = t >> 4;
    float acc[4][4];
    #pragma unroll
    for (int r = 0; r < 4; ++r)
        #pragma unroll
        for (int c = 0; c < 4; ++c) acc[r][c] = 0.f;

    for (int k0 = 0; k0 < C1; k0 += 32) {
        __syncthreads();
        #pragma unroll
        for (int s = 0; s < 2; ++s) {
            int q = t + 256 * s;
            int row = q >> 3, kq = (q & 7) * 4;
            float4 a4 = *(const float4*)&in1d[(size_t)(n0 + row) * C1 + k0 + kq];
            ASt[kq + 0][row] = a4.x; ASt[kq + 1][row] = a4.y;
            ASt[kq + 2][row] = a4.z; ASt[kq + 3][row] = a4.w;
            const float* wr; float bb;
            wsel(o0 + row, w_qs, b_qs, w_kvs, b_kvs, w_qp, b_qp, w_kvp, b_kvp, &wr, &bb);
            float4 w4 = *(const float4*)&wr[k0 + kq];
            WSt[kq + 0][row] = w4.x; WSt[kq + 1][row] = w4.y;
            WSt[kq + 2][row] = w4.z; WSt[kq + 3][row] = w4.w;
        }
        __syncthreads();
        #pragma unroll
        for (int k = 0; k < 32; ++k) {
            float4 a4 = *(const float4*)&ASt[k][ty * 4];
            float4 w4 = *(const float4*)&WSt[k][tx * 4];
            float av[4] = {a4.x, a4.y, a4.z, a4.w};
            float wv[4] = {w4.x, w4.y, w4.z, w4.w};
            #pragma unroll
            for (int r = 0; r < 4; ++r)
                #pragma unroll
                for (int c = 0; c < 4; ++c)
                    acc[r][c] = fmaf(av[r], wv[c], acc[r][c]);
        }
    }
    float bias[4];
    #pragma unroll
    for (int c = 0; c < 4; ++c) {
        const float* dummy;
        wsel(o0 + tx * 4 + c, w_qs, b_qs, w_kvs, b_kvs, w_qp, b_qp, w_kvp, b_kvp, &dummy, &bias[c]);
    }
    float* raw = ws + OFF_RAW;
    #pragma unroll
    for (int r = 0; r < 4; ++r) {
        int n = n0 + ty * 4 + r;
        *(float4*)&raw[(size_t)n * 1152 + o0 + tx * 4] =
            make_float4(acc[r][0] + bias[0], acc[r][1] + bias[1],
                        acc[r][2] + bias[2], acc[r][3] + bias[3]);
    }
}

// ---------------------------------------------------------------------------
// K1b: scatter raw projections into qs/ks/vs and apply global frame to points.
// ---------------------------------------------------------------------------
__global__ __launch_bounds__(256) void k1b_scatter(
    const float* __restrict__ rot, const float* __restrict__ trans,
    float* __restrict__ ws)
{
    __shared__ __align__(16) float rawS[1152];
    const int t = threadIdx.x;
    const int i = blockIdx.x;
    const float* raw = ws + OFF_RAW + (size_t)i * 1152;
    for (int q = t; q < 288; q += 256) *(float4*)&rawS[q * 4] = *(const float4*)&raw[q * 4];
    __syncthreads();
    float* qs  = ws + OFF_QS;  float* ks  = ws + OFF_KS;  float* vs  = ws + OFF_VS;
    float* qpt = ws + OFF_QPT; float* kpt = ws + OFF_KPT; float* vpt = ws + OFF_VPT;

    for (int o = t; o < 576; o += 256) {
        float v = rawS[o];
        if (o < 192) {
            qs[(size_t)i * 192 + o] = v * SCALAR_W;
        } else {
            int idx = o - 192, h = idx >> 5, d = idx & 31;
            if (d < 16) ks[(size_t)i * 192 + h * 16 + d] = v;
            else        vs[(size_t)i * 192 + h * 16 + (d - 16)] = v;
        }
    }
    if (t < 192) {
        int m = t;
        float x0, x1, x2;
        if (m < 48) { x0 = rawS[576 + m]; x1 = rawS[624 + m]; x2 = rawS[672 + m]; }
        else { int mm = m - 48; x0 = rawS[720 + mm]; x1 = rawS[864 + mm]; x2 = rawS[1008 + mm]; }
        float g[3];
        #pragma unroll
        for (int ii = 0; ii < 3; ++ii)
            g[ii] = rot[i * 9 + ii * 3 + 0] * x0 + rot[i * 9 + ii * 3 + 1] * x1 +
                    rot[i * 9 + ii * 3 + 2] * x2 + trans[i * 3 + ii];
        if (m < 48) {
            #pragma unroll
            for (int ii = 0; ii < 3; ++ii) qpt[(size_t)i * 144 + 3 * m + ii] = g[ii];
        } else {
            int mm = m - 48, h = mm / 12, pp = mm % 12;
            if (pp < 4) {
                #pragma unroll
                for (int ii = 0; ii < 3; ++ii) kpt[(size_t)i * 144 + h * 12 + pp * 3 + ii] = g[ii];
            } else {
                #pragma unroll
                for (int ii = 0; ii < 3; ++ii) vpt[(size_t)i * 288 + h * 24 + (pp - 4) * 3 + ii] = g[ii];
            }
        }
    }
}

// ---------------------------------------------------------------------------
// K2: head-split (6 heads/block) fused online-softmax IPA.
// grid (768, 2): block (i, hg). Pair blocks (i,0)/(i,1) have linear IDs i and
// i+768 == i (mod 8) -> SAME XCD -> shared L2 for in2d[i] (kills R3's 3x
// traffic). Phase A: R3's verified scattered-read logits (6 heads). Phase B:
// R0's verified staged-tileS weighting, 32-row sub-stages (LDS ~24.8KB ->
// 6 blocks/CU -> 24 waves/CU latency hiding).
// ---------------------------------------------------------------------------
__global__ __launch_bounds__(256, 6) void k2_attn(
    const float* __restrict__ in2d,
    const float* __restrict__ mask,
    const float* __restrict__ rot, const float* __restrict__ trans,
    const float* __restrict__ tpw,
    const float* __restrict__ w2d, const float* __restrict__ b2d,
    float* __restrict__ ws)
{
    __shared__ __align__(16) float tileS[32][128];   // 16.4 KB staged in2d sub-tile
    __shared__ __align__(16) float P[HB][264];       // logits -> exp weights
    __shared__ __align__(16) float qsS[192];
    __shared__ __align__(16) float qptS[144];
    __shared__ float qnS[HB], phS[HB], bbS[HB], mS[HB], lS[HB], aS[HB];
    __shared__ float rpgS[144];                      // 6 heads x 8 p x 3
    const int t  = threadIdx.x;
    const int i  = blockIdx.x;
    const int hg = blockIdx.y;
    const int h0 = hg * HB;

    const float* qs  = ws + OFF_QS;  const float* ks  = ws + OFF_KS;  const float* vs = ws + OFF_VS;
    const float* qpt = ws + OFF_QPT; const float* kpt = ws + OFF_KPT; const float* vpt = ws + OFF_VPT;

    if (t < 48) *(float4*)&qsS[t * 4] = *(const float4*)&qs[(size_t)i * 192 + t * 4];
    else if (t >= 64 && t < 100) { int u = t - 64; *(float4*)&qptS[u * 4] = *(const float4*)&qpt[(size_t)i * 144 + u * 4]; }
    __syncthreads();
    if (t < HB) {
        int h = h0 + t;
        float s = 0.f;
        #pragma unroll
        for (int e = 0; e < 12; ++e) { float x = qptS[h * 12 + e]; s += x * x; }
        qnS[t] = s;
        phS[t] = -0.5f * POINT_W * logf(1.f + __expf(tpw[h]));
        bbS[t] = W2D_W * b2d[h];
        mS[t] = -1e30f;
        lS[t] = 0.f;
    }
    __syncthreads();
    const float mi = mask[i];

    // persistent accumulators (unnormalized, rescaled by alpha each tile)
    float ra[4] = {0.f, 0.f, 0.f, 0.f};
    float rb[4] = {0.f, 0.f, 0.f, 0.f};
    const bool isR2 = (t < 192);
    int lh = 0, c4 = 0, o0 = 0, q0 = 0, vh = 0;
    const float* vbase = nullptr; int vstride = 0; bool vact = false;
    if (isR2) { lh = t >> 5; c4 = t & 31; }           // one local head per thread group
    else {
        int u = t - 192; vact = (u < 30); o0 = u * 8;
        if (vact) {
            if (u < 12) { vh = u >> 1; vbase = vs + (size_t)h0 * 16 + o0; vstride = 192; }
            else { q0 = o0 - 96; vh = q0 / 24; vbase = vpt + (size_t)h0 * 24 + q0; vstride = 288; }
        }
    }

    for (int tile = 0; tile < 3; ++tile) {
        const int j0 = tile * 256;
        __syncthreads();   // P reuse safety across tiles
        // ---- phase A: logits for j = j0 + t, local heads 0..5 (scattered
        //      global reads; twin block on same XCD makes these L2 hits) ----
        {
            const int j = j0 + t;
            float acc[HB];
            #pragma unroll
            for (int g = 0; g < HB; ++g) acc[g] = 0.f;
            const float* row   = in2d + ((size_t)i * NRES + j) * C2;
            const float* wbase = w2d + (size_t)h0 * C2;
            #pragma unroll 8
            for (int cc = 0; cc < 32; ++cc) {
                float4 v4 = *(const float4*)&row[cc * 4];
                #pragma unroll
                for (int g = 0; g < HB; ++g) {
                    float4 w4 = *(const float4*)&wbase[g * C2 + cc * 4];  // wave-uniform -> s_load
                    acc[g] += dot4(v4, w4);
                }
            }
            const float msub = -100000.0f * (1.0f - mi * mask[j]);
            const float* ksr  = ks  + (size_t)j * 192 + h0 * 16;
            const float* kptr = kpt + (size_t)j * 144 + h0 * 12;
            #pragma unroll
            for (int g = 0; g < HB; ++g) {
                float sq = 0.f;
                #pragma unroll
                for (int d4 = 0; d4 < 4; ++d4) {
                    float4 q4 = *(const float4*)&qsS[(h0 + g) * 16 + d4 * 4];
                    float4 k4 = *(const float4*)&ksr[g * 16 + d4 * 4];
                    sq += dot4(q4, k4);
                }
                float qk = 0.f, kk = 0.f;
                #pragma unroll
                for (int e4 = 0; e4 < 3; ++e4) {
                    float4 qp4 = *(const float4*)&qptS[(h0 + g) * 12 + e4 * 4];
                    float4 kp4 = *(const float4*)&kptr[g * 12 + e4 * 4];
                    qk += dot4(qp4, kp4);
                    kk += dot4(kp4, kp4);
                }
                P[g][t] = sq + phS[g] * (qnS[g] + kk - 2.f * qk) + W2D_W * acc[g] + bbS[g] + msub;
            }
        }
        __syncthreads();
        // ---- online softmax update: wave wv handles local heads wv, wv+4 ----
        {
            int wv = t >> 6, lane = t & 63;
            for (int g = wv; g < HB; g += 4) {
                float v0 = P[g][lane], v1 = P[g][lane + 64], v2 = P[g][lane + 128], v3 = P[g][lane + 192];
                float mt = fmaxf(fmaxf(v0, v1), fmaxf(v2, v3));
                #pragma unroll
                for (int off = 32; off > 0; off >>= 1) mt = fmaxf(mt, __shfl_xor(mt, off));
                float mold = mS[g];
                float mnew = fmaxf(mold, mt);
                float e0 = __expf(v0 - mnew), e1 = __expf(v1 - mnew);
                float e2 = __expf(v2 - mnew), e3 = __expf(v3 - mnew);
                P[g][lane] = e0; P[g][lane + 64] = e1; P[g][lane + 128] = e2; P[g][lane + 192] = e3;
                float s = e0 + e1 + e2 + e3;
                #pragma unroll
                for (int off = 32; off > 0; off >>= 1) s += __shfl_xor(s, off);
                if (lane == 0) {
                    float a = __expf(mold - mnew);
                    aS[g] = a;
                    lS[g] = lS[g] * a + s;
                    mS[g] = mnew;
                }
            }
        }
        __syncthreads();
        // ---- rescale persistent accumulators once per tile ----
        if (isR2) {
            float a = aS[lh];
            #pragma unroll
            for (int k = 0; k < 4; ++k) ra[k] *= a;
        } else if (vact) {
            float a = aS[vh];
            #pragma unroll
            for (int k = 0; k < 4; ++k) { ra[k] *= a; rb[k] *= a; }
        }
        // ---- phase B: 8 staged sub-tiles of 32 rows (reads are L2-hot) ----
        for (int sub = 0; sub < 8; ++sub) {
            __syncthreads();
            #pragma unroll
            for (int u2 = 0; u2 < 4; ++u2) {
                int q = u2 * 256 + t;
                int rr = q >> 5, cc = q & 31;
                *(float4*)&tileS[rr][cc * 4] =
                    *(const float4*)&in2d[((size_t)i * NRES + j0 + sub * 32 + rr) * C2 + cc * 4];
            }
            __syncthreads();
            if (isR2) {
                for (int jj = 0; jj < 32; jj += 4) {
                    int jt = sub * 32 + jj;
                    float4 p4 = *(const float4*)&P[lh][jt];
                    float w[4] = {p4.x, p4.y, p4.z, p4.w};
                    #pragma unroll
                    for (int k = 0; k < 4; ++k) {
                        float4 v4 = *(const float4*)&tileS[jj + k][c4 * 4];
                        ra[0] = fmaf(w[k], v4.x, ra[0]); ra[1] = fmaf(w[k], v4.y, ra[1]);
                        ra[2] = fmaf(w[k], v4.z, ra[2]); ra[3] = fmaf(w[k], v4.w, ra[3]);
                    }
                }
            } else if (vact) {
                for (int jj = 0; jj < 32; jj += 4) {
                    int jt = sub * 32 + jj;
                    int jg = j0 + jt;
                    float4 p = *(const float4*)&P[vh][jt];
                    float w[4] = {p.x, p.y, p.z, p.w};
                    #pragma unroll
                    for (int k = 0; k < 4; ++k) {
                        float4 va4 = *(const float4*)&vbase[(size_t)(jg + k) * vstride];
                        float4 vb4 = *(const float4*)&vbase[(size_t)(jg + k) * vstride + 4];
                        ra[0] = fmaf(w[k], va4.x, ra[0]); ra[1] = fmaf(w[k], va4.y, ra[1]);
                        ra[2] = fmaf(w[k], va4.z, ra[2]); ra[3] = fmaf(w[k], va4.w, ra[3]);
                        rb[0] = fmaf(w[k], vb4.x, rb[0]); rb[1] = fmaf(w[k], vb4.y, rb[1]);
                        rb[2] = fmaf(w[k], vb4.z, rb[2]); rb[3] = fmaf(w[k], vb4.w, rb[3]);
                    }
                }
            }
        }
    }
    // ---- finalize (this block writes only its 6 heads' slices of fa) ----
    float* fa = ws + OFF_FA + (size_t)i * 2112;
    if (isR2) {
        float nv = 1.f / lS[lh];
        *(float4*)&fa[576 + (h0 + lh) * 128 + c4 * 4] = make_float4(ra[0] * nv, ra[1] * nv, ra[2] * nv, ra[3] * nv);
    } else if (vact) {
        float nv = 1.f / lS[vh];
        if (o0 < 96) {  // sv slice: global cols h0*16 + [0,96)
            *(float4*)&fa[h0 * 16 + o0]     = make_float4(ra[0] * nv, ra[1] * nv, ra[2] * nv, ra[3] * nv);
            *(float4*)&fa[h0 * 16 + o0 + 4] = make_float4(rb[0] * nv, rb[1] * nv, rb[2] * nv, rb[3] * nv);
        } else {        // pv slice -> local rpgS[144]
            *(float4*)&rpgS[q0]     = make_float4(ra[0] * nv, ra[1] * nv, ra[2] * nv, ra[3] * nv);
            *(float4*)&rpgS[q0 + 4] = make_float4(rb[0] * nv, rb[1] * nv, rb[2] * nv, rb[3] * nv);
        }
    }
    __syncthreads();
    if (t < 48) {
        int g = t >> 3, p = t & 7;
        int gh = h0 + g;
        float rv[3];
        #pragma unroll
        for (int c = 0; c < 3; ++c) rv[c] = rpgS[g * 24 + p * 3 + c] - trans[i * 3 + c];
        float l0 = rot[i * 9 + 0] * rv[0] + rot[i * 9 + 3] * rv[1] + rot[i * 9 + 6] * rv[2];
        float l1 = rot[i * 9 + 1] * rv[0] + rot[i * 9 + 4] * rv[1] + rot[i * 9 + 7] * rv[2];
        float l2 = rot[i * 9 + 2] * rv[0] + rot[i * 9 + 5] * rv[1] + rot[i * 9 + 8] * rv[2];
        float dd = sqrtf(1e-8f + l0 * l0 + l1 * l1 + l2 * l2);
        fa[192 + gh * 8 + p] = l0;
        fa[288 + gh * 8 + p] = l1;
        fa[384 + gh * 8 + p] = l2;
        fa[480 + gh * 8 + p] = dd;
    }
}

// ---------------------------------------------------------------------------
// K3: out = final_act @ w_out.T + b_out.  32x32 tiles, 2x2 micro-tile.
// ---------------------------------------------------------------------------
__global__ __launch_bounds__(256) void k3_out(
    const float* __restrict__ w_out, const float* __restrict__ b_out,
    const float* __restrict__ ws, float* __restrict__ out)
{
    __shared__ __align__(16) float ASt[32][34];
    __shared__ __align__(16) float WSt[32][34];
    const int t = threadIdx.x;
    const int i0 = blockIdx.x * 32;
    const int o0 = blockIdx.y * 32;
    const float* fa = ws + OFF_FA;
    int tx = t & 15, ty = t >> 4;
    float acc00 = 0.f, acc01 = 0.f, acc10 = 0.f, acc11 = 0.f;
    int r = t >> 3, kq = (t & 7) * 4;

    for (int k0 = 0; k0 < 2112; k0 += 32) {
        __syncthreads();
        {
            float4 a4 = *(const float4*)&fa[(size_t)(i0 + r) * 2112 + k0 + kq];
            ASt[kq + 0][r] = a4.x; ASt[kq + 1][r] = a4.y; ASt[kq + 2][r] = a4.z; ASt[kq + 3][r] = a4.w;
            float4 w4 = *(const float4*)&w_out[(size_t)(o0 + r) * 2112 + k0 + kq];
            WSt[kq + 0][r] = w4.x; WSt[kq + 1][r] = w4.y; WSt[kq + 2][r] = w4.z; WSt[kq + 3][r] = w4.w;
        }
        __syncthreads();
        #pragma unroll
        for (int k = 0; k < 32; ++k) {
            float2 av = *(const float2*)&ASt[k][ty * 2];
            float2 wv = *(const float2*)&WSt[k][tx * 2];
            acc00 = fmaf(av.x, wv.x, acc00);
            acc01 = fmaf(av.x, wv.y, acc01);
            acc10 = fmaf(av.y, wv.x, acc10);
            acc11 = fmaf(av.y, wv.y, acc11);
        }
    }
    int oi = i0 + ty * 2, oo = o0 + tx * 2;
    out[(size_t)oi * 384 + oo]           = acc00 + b_out[oo];
    out[(size_t)oi * 384 + oo + 1]       = acc01 + b_out[oo + 1];
    out[(size_t)(oi + 1) * 384 + oo]     = acc10 + b_out[oo];
    out[(size_t)(oi + 1) * 384 + oo + 1] = acc11 + b_out[oo + 1];
}

extern "C" void kernel_launch(void* const* d_in, const int* in_sizes, int n_in,
                              void* d_out, int out_size, void* d_ws, size_t ws_size,
                              hipStream_t stream) {
    const float* in1d  = (const float*)d_in[0];
    const float* in2d  = (const float*)d_in[1];
    const float* mask  = (const float*)d_in[2];
    const float* rot   = (const float*)d_in[3];
    const float* trans = (const float*)d_in[4];
    const float* w_qs  = (const float*)d_in[5];
    const float* b_qs  = (const float*)d_in[6];
    const float* w_kvs = (const float*)d_in[7];
    const float* b_kvs = (const float*)d_in[8];
    const float* w_qp  = (const float*)d_in[9];
    const float* b_qp  = (const float*)d_in[10];
    const float* w_kvp = (const float*)d_in[11];
    const float* b_kvp = (const float*)d_in[12];
    const float* tpw   = (const float*)d_in[13];
    const float* w2d   = (const float*)d_in[14];
    const float* b2d   = (const float*)d_in[15];
    const float* w_out = (const float*)d_in[16];
    const float* b_out = (const float*)d_in[17];
    float* ws  = (float*)d_ws;
    float* out = (float*)d_out;

    hipLaunchKernelGGL(k1_gemm, dim3(12, 18), dim3(256), 0, stream,
                       in1d, w_qs, b_qs, w_kvs, b_kvs, w_qp, b_qp, w_kvp, b_kvp, ws);
    hipLaunchKernelGGL(k1b_scatter, dim3(768), dim3(256), 0, stream,
                       rot, trans, ws);
    hipLaunchKernelGGL(k2_attn, dim3(768, 2), dim3(256), 0, stream,
                       in2d, mask, rot, trans, tpw, w2d, b2d, ws);
    hipLaunchKernelGGL(k3_out, dim3(24, 12), dim3(256), 0, stream,
                       w_out, b_out, ws, out);
}

// Round 6
// 800.124 us; speedup vs baseline: 1.1028x; 1.1028x over previous
//
#include <hip/hip_runtime.h>
#include <hip/hip_bf16.h>
#include <math.h>

#define NRES 768
#define C1 384
#define C2 128
#define NH 12

// ws float offsets (UNCHANGED verified layout — no growth)
#define OFF_QS   0          // 768*192
#define OFF_KS   147456
#define OFF_VS   294912
#define OFF_QPT  442368     // 768*144
#define OFF_KPT  552960
#define OFF_VPT  663552     // 768*288
#define OFF_FA   884736     // 768*2112
#define OFF_RAW  OFF_FA     // raw projections aliased into fa region

__device__ __forceinline__ float dot4(float4 a, float4 b) {
    return fmaf(a.x, b.x, fmaf(a.y, b.y, fmaf(a.z, b.z, a.w * b.w)));
}

static constexpr float SCALAR_W = 0.14433756729740643f; // sqrt(1/48)
static constexpr float POINT_W  = 0.13608276348795434f; // sqrt(1/54)
static constexpr float W2D_W    = 0.57735026918962576f; // sqrt(1/3)

__device__ __forceinline__ void wsel(int o,
    const float* w_qs, const float* b_qs, const float* w_kvs, const float* b_kvs,
    const float* w_qp, const float* b_qp, const float* w_kvp, const float* b_kvp,
    const float** row, float* bias)
{
    if (o < 192)      { *row = w_qs  + (size_t)o * C1;         *bias = b_qs[o]; }
    else if (o < 576) { *row = w_kvs + (size_t)(o - 192) * C1; *bias = b_kvs[o - 192]; }
    else if (o < 720) { *row = w_qp  + (size_t)(o - 576) * C1; *bias = b_qp[o - 576]; }
    else              { *row = w_kvp + (size_t)(o - 720) * C1; *bias = b_kvp[o - 720]; }
}

// ---------------------------------------------------------------------------
// K1: raw = in1d @ W_all.T + b_all  (768 x 1152, K=384), tiled GEMM.
// ---------------------------------------------------------------------------
__global__ __launch_bounds__(256) void k1_gemm(
    const float* __restrict__ in1d,
    const float* __restrict__ w_qs, const float* __restrict__ b_qs,
    const float* __restrict__ w_kvs, const float* __restrict__ b_kvs,
    const float* __restrict__ w_qp, const float* __restrict__ b_qp,
    const float* __restrict__ w_kvp, const float* __restrict__ b_kvp,
    float* __restrict__ ws)
{
    __shared__ __align__(16) float ASt[32][68];
    __shared__ __align__(16) float WSt[32][68];
    const int t = threadIdx.x;
    const int n0 = blockIdx.x * 64;
    const int o0 = blockIdx.y * 64;
    const int tx = t & 15, ty = t >> 4;
    float acc[4][4];
    #pragma unroll
    for (int r = 0; r < 4; ++r)
        #pragma unroll
        for (int c = 0; c < 4; ++c) acc[r][c] = 0.f;

    for (int k0 = 0; k0 < C1; k0 += 32) {
        __syncthreads();
        #pragma unroll
        for (int s = 0; s < 2; ++s) {
            int q = t + 256 * s;
            int row = q >> 3, kq = (q & 7) * 4;
            float4 a4 = *(const float4*)&in1d[(size_t)(n0 + row) * C1 + k0 + kq];
            ASt[kq + 0][row] = a4.x; ASt[kq + 1][row] = a4.y;
            ASt[kq + 2][row] = a4.z; ASt[kq + 3][row] = a4.w;
            const float* wr; float bb;
            wsel(o0 + row, w_qs, b_qs, w_kvs, b_kvs, w_qp, b_qp, w_kvp, b_kvp, &wr, &bb);
            float4 w4 = *(const float4*)&wr[k0 + kq];
            WSt[kq + 0][row] = w4.x; WSt[kq + 1][row] = w4.y;
            WSt[kq + 2][row] = w4.z; WSt[kq + 3][row] = w4.w;
        }
        __syncthreads();
        #pragma unroll
        for (int k = 0; k < 32; ++k) {
            float4 a4 = *(const float4*)&ASt[k][ty * 4];
            float4 w4 = *(const float4*)&WSt[k][tx * 4];
            float av[4] = {a4.x, a4.y, a4.z, a4.w};
            float wv[4] = {w4.x, w4.y, w4.z, w4.w};
            #pragma unroll
            for (int r = 0; r < 4; ++r)
                #pragma unroll
                for (int c = 0; c < 4; ++c)
                    acc[r][c] = fmaf(av[r], wv[c], acc[r][c]);
        }
    }
    float bias[4];
    #pragma unroll
    for (int c = 0; c < 4; ++c) {
        const float* dummy;
        wsel(o0 + tx * 4 + c, w_qs, b_qs, w_kvs, b_kvs, w_qp, b_qp, w_kvp, b_kvp, &dummy, &bias[c]);
    }
    float* raw = ws + OFF_RAW;
    #pragma unroll
    for (int r = 0; r < 4; ++r) {
        int n = n0 + ty * 4 + r;
        *(float4*)&raw[(size_t)n * 1152 + o0 + tx * 4] =
            make_float4(acc[r][0] + bias[0], acc[r][1] + bias[1],
                        acc[r][2] + bias[2], acc[r][3] + bias[3]);
    }
}

// ---------------------------------------------------------------------------
// K1b: scatter raw projections into qs/ks/vs and apply global frame to points.
// ---------------------------------------------------------------------------
__global__ __launch_bounds__(256) void k1b_scatter(
    const float* __restrict__ rot, const float* __restrict__ trans,
    float* __restrict__ ws)
{
    __shared__ __align__(16) float rawS[1152];
    const int t = threadIdx.x;
    const int i = blockIdx.x;
    const float* raw = ws + OFF_RAW + (size_t)i * 1152;
    for (int q = t; q < 288; q += 256) *(float4*)&rawS[q * 4] = *(const float4*)&raw[q * 4];
    __syncthreads();
    float* qs  = ws + OFF_QS;  float* ks  = ws + OFF_KS;  float* vs  = ws + OFF_VS;
    float* qpt = ws + OFF_QPT; float* kpt = ws + OFF_KPT; float* vpt = ws + OFF_VPT;

    for (int o = t; o < 576; o += 256) {
        float v = rawS[o];
        if (o < 192) {
            qs[(size_t)i * 192 + o] = v * SCALAR_W;
        } else {
            int idx = o - 192, h = idx >> 5, d = idx & 31;
            if (d < 16) ks[(size_t)i * 192 + h * 16 + d] = v;
            else        vs[(size_t)i * 192 + h * 16 + (d - 16)] = v;
        }
    }
    if (t < 192) {
        int m = t;
        float x0, x1, x2;
        if (m < 48) { x0 = rawS[576 + m]; x1 = rawS[624 + m]; x2 = rawS[672 + m]; }
        else { int mm = m - 48; x0 = rawS[720 + mm]; x1 = rawS[864 + mm]; x2 = rawS[1008 + mm]; }
        float g[3];
        #pragma unroll
        for (int ii = 0; ii < 3; ++ii)
            g[ii] = rot[i * 9 + ii * 3 + 0] * x0 + rot[i * 9 + ii * 3 + 1] * x1 +
                    rot[i * 9 + ii * 3 + 2] * x2 + trans[i * 3 + ii];
        if (m < 48) {
            #pragma unroll
            for (int ii = 0; ii < 3; ++ii) qpt[(size_t)i * 144 + 3 * m + ii] = g[ii];
        } else {
            int mm = m - 48, h = mm / 12, pp = mm % 12;
            if (pp < 4) {
                #pragma unroll
                for (int ii = 0; ii < 3; ++ii) kpt[(size_t)i * 144 + h * 12 + pp * 3 + ii] = g[ii];
            } else {
                #pragma unroll
                for (int ii = 0; ii < 3; ++ii) vpt[(size_t)i * 288 + h * 24 + (pp - 4) * 3 + ii] = g[ii];
            }
        }
    }
}

// ---------------------------------------------------------------------------
// K2: R0's verified fused single-pass online-softmax IPA row kernel, with ONE
// change: phase-B staging sub-tiles shrunk 64->32 rows (8 sub-stages). LDS
// 48.6 -> ~31.8 KB => 5 blocks/CU (20 waves/CU vs R0's 12) for latency hiding.
// Traffic stays single-pass (1 block per i; phase-B re-reads hit L3).
// ---------------------------------------------------------------------------
#define TJ 256
__global__ __launch_bounds__(256) void k2_attn(
    const float* __restrict__ in2d,
    const float* __restrict__ mask,
    const float* __restrict__ rot, const float* __restrict__ trans,
    const float* __restrict__ tpw,
    const float* __restrict__ w2d, const float* __restrict__ b2d,
    float* __restrict__ ws)
{
    __shared__ __align__(16) float P[NH][264];       // logits -> exp weights
    __shared__ __align__(16) float tileS[32][128];   // in2d subtile (16.4 KB)
    __shared__ __align__(16) float qsS[192];
    __shared__ __align__(16) float qptS[144];
    __shared__ float qnS[NH], phS[NH], bbS[NH], mS[NH], lS[NH], aS[NH];
    __shared__ float rpgS[288];
    const int t = threadIdx.x;
    const int i = blockIdx.x;

    const float* qs  = ws + OFF_QS;  const float* ks  = ws + OFF_KS;  const float* vs = ws + OFF_VS;
    const float* qpt = ws + OFF_QPT; const float* kpt = ws + OFF_KPT; const float* vpt = ws + OFF_VPT;

    if (t < 48) *(float4*)&qsS[t * 4] = *(const float4*)&qs[(size_t)i * 192 + t * 4];
    else if (t >= 64 && t < 100) { int u = t - 64; *(float4*)&qptS[u * 4] = *(const float4*)&qpt[(size_t)i * 144 + u * 4]; }
    __syncthreads();
    if (t < NH) {
        float s = 0.f;
        #pragma unroll
        for (int e = 0; e < 12; ++e) { float x = qptS[t * 12 + e]; s += x * x; }
        qnS[t] = s;
        phS[t] = -0.5f * POINT_W * logf(1.f + __expf(tpw[t]));
        bbS[t] = W2D_W * b2d[t];
        mS[t] = -1e30f;
        lS[t] = 0.f;
    }
    __syncthreads();
    const float mi = mask[i];

    // persistent accumulators (unnormalized, rescaled by alpha each tile)
    float ra[4] = {0.f, 0.f, 0.f, 0.f};
    float rb[4] = {0.f, 0.f, 0.f, 0.f};
    const bool isR2 = (t < 192);
    int h0 = 0, h1 = 0, c4 = 0, o0 = 0, vh = 0;
    const float* vbase = nullptr; int vstride = 0; bool vact = false;
    if (isR2) { h0 = (t >> 5) * 2; h1 = h0 + 1; c4 = t & 31; }
    else {
        int u = t - 192; o0 = u * 8; vact = (u < 60);
        if (vact) {
            if (o0 < 192) { vh = o0 >> 4; vbase = vs + o0; vstride = 192; }
            else { int q0 = o0 - 192; vh = q0 / 24; vbase = vpt + q0; vstride = 288; }
        }
    }

    for (int tile = 0; tile < 3; ++tile) {
        const int j0 = tile * TJ;
        __syncthreads();   // P reuse safety across tiles
        // ---- phase A: logits for j = j0 + t ----
        {
            const int j = j0 + t;
            float acc[NH];
            #pragma unroll
            for (int h = 0; h < NH; ++h) acc[h] = 0.f;
            const float* row = in2d + ((size_t)i * NRES + j) * C2;
            #pragma unroll 8
            for (int cc = 0; cc < 32; ++cc) {
                float4 v4 = *(const float4*)&row[cc * 4];
                #pragma unroll
                for (int h = 0; h < NH; ++h) {
                    float4 w4 = *(const float4*)&w2d[h * C2 + cc * 4];  // wave-uniform -> s_load
                    acc[h] += dot4(v4, w4);
                }
            }
            const float msub = -100000.0f * (1.0f - mi * mask[j]);
            const float* ksr  = ks  + (size_t)j * 192;
            const float* kptr = kpt + (size_t)j * 144;
            #pragma unroll
            for (int h = 0; h < NH; ++h) {
                float sq = 0.f;
                #pragma unroll
                for (int d4 = 0; d4 < 4; ++d4) {
                    float4 q4 = *(const float4*)&qsS[h * 16 + d4 * 4];
                    float4 k4 = *(const float4*)&ksr[h * 16 + d4 * 4];
                    sq += dot4(q4, k4);
                }
                float qk = 0.f, kk = 0.f;
                #pragma unroll
                for (int e4 = 0; e4 < 3; ++e4) {
                    float4 qp4 = *(const float4*)&qptS[h * 12 + e4 * 4];
                    float4 kp4 = *(const float4*)&kptr[h * 12 + e4 * 4];
                    qk += dot4(qp4, kp4);
                    kk += dot4(kp4, kp4);
                }
                P[h][t] = sq + phS[h] * (qnS[h] + kk - 2.f * qk) + W2D_W * acc[h] + bbS[h] + msub;
            }
        }
        __syncthreads();
        // ---- online softmax update over this tile: wave wv handles 3 heads ----
        {
            int wv = t >> 6, lane = t & 63;
            for (int h = wv * 3; h < wv * 3 + 3; ++h) {
                float v0 = P[h][lane], v1 = P[h][lane + 64], v2 = P[h][lane + 128], v3 = P[h][lane + 192];
                float mt = fmaxf(fmaxf(v0, v1), fmaxf(v2, v3));
                #pragma unroll
                for (int off = 32; off > 0; off >>= 1) mt = fmaxf(mt, __shfl_xor(mt, off));
                float mold = mS[h];
                float mnew = fmaxf(mold, mt);
                float e0 = __expf(v0 - mnew), e1 = __expf(v1 - mnew);
                float e2 = __expf(v2 - mnew), e3 = __expf(v3 - mnew);
                P[h][lane] = e0; P[h][lane + 64] = e1; P[h][lane + 128] = e2; P[h][lane + 192] = e3;
                float s = e0 + e1 + e2 + e3;
                #pragma unroll
                for (int off = 32; off > 0; off >>= 1) s += __shfl_xor(s, off);
                if (lane == 0) {
                    float a = __expf(mold - mnew);
                    aS[h] = a;
                    lS[h] = lS[h] * a + s;
                    mS[h] = mnew;
                }
            }
        }
        __syncthreads();
        // ---- rescale persistent accumulators ----
        if (isR2) {
            float a0 = aS[h0], a1 = aS[h1];
            #pragma unroll
            for (int k = 0; k < 4; ++k) { ra[k] *= a0; rb[k] *= a1; }
        } else if (vact) {
            float a = aS[vh];
            #pragma unroll
            for (int k = 0; k < 4; ++k) { ra[k] *= a; rb[k] *= a; }
        }
        // ---- phase B: apply weights, 8 staged subtiles of 32 rows (L3-hot) ----
        for (int sub = 0; sub < 8; ++sub) {
            __syncthreads();
            #pragma unroll
            for (int s = 0; s < 4; ++s) {
                int q = t + 256 * s;
                int rr = q >> 5, cc = q & 31;
                *(float4*)&tileS[rr][cc * 4] =
                    *(const float4*)&in2d[((size_t)i * NRES + j0 + sub * 32 + rr) * C2 + cc * 4];
            }
            __syncthreads();
            if (isR2) {
                for (int jj = 0; jj < 32; jj += 4) {
                    int jt = sub * 32 + jj;
                    float4 p0 = *(const float4*)&P[h0][jt];
                    float4 p1 = *(const float4*)&P[h1][jt];
                    float w0[4] = {p0.x, p0.y, p0.z, p0.w};
                    float w1[4] = {p1.x, p1.y, p1.z, p1.w};
                    #pragma unroll
                    for (int k = 0; k < 4; ++k) {
                        float4 v4 = *(const float4*)&tileS[jj + k][c4 * 4];
                        ra[0] = fmaf(w0[k], v4.x, ra[0]); ra[1] = fmaf(w0[k], v4.y, ra[1]);
                        ra[2] = fmaf(w0[k], v4.z, ra[2]); ra[3] = fmaf(w0[k], v4.w, ra[3]);
                        rb[0] = fmaf(w1[k], v4.x, rb[0]); rb[1] = fmaf(w1[k], v4.y, rb[1]);
                        rb[2] = fmaf(w1[k], v4.z, rb[2]); rb[3] = fmaf(w1[k], v4.w, rb[3]);
                    }
                }
            } else if (vact) {
                for (int jj = 0; jj < 32; jj += 4) {
                    int jt = sub * 32 + jj;
                    int jg = j0 + jt;
                    float4 p = *(const float4*)&P[vh][jt];
                    float w[4] = {p.x, p.y, p.z, p.w};
                    #pragma unroll
                    for (int k = 0; k < 4; ++k) {
                        float4 va = *(const float4*)&vbase[(size_t)(jg + k) * vstride];
                        float4 vb = *(const float4*)&vbase[(size_t)(jg + k) * vstride + 4];
                        ra[0] = fmaf(w[k], va.x, ra[0]); ra[1] = fmaf(w[k], va.y, ra[1]);
                        ra[2] = fmaf(w[k], va.z, ra[2]); ra[3] = fmaf(w[k], va.w, ra[3]);
                        rb[0] = fmaf(w[k], vb.x, rb[0]); rb[1] = fmaf(w[k], vb.y, rb[1]);
                        rb[2] = fmaf(w[k], vb.z, rb[2]); rb[3] = fmaf(w[k], vb.w, rb[3]);
                    }
                }
            }
        }
    }
    // ---- finalize ----
    float* fa = ws + OFF_FA + (size_t)i * 2112;
    if (isR2) {
        float n0v = 1.f / lS[h0], n1v = 1.f / lS[h1];
        *(float4*)&fa[576 + h0 * 128 + c4 * 4] = make_float4(ra[0] * n0v, ra[1] * n0v, ra[2] * n0v, ra[3] * n0v);
        *(float4*)&fa[576 + h1 * 128 + c4 * 4] = make_float4(rb[0] * n1v, rb[1] * n1v, rb[2] * n1v, rb[3] * n1v);
    } else if (vact) {
        float nv = 1.f / lS[vh];
        if (o0 < 192) {
            *(float4*)&fa[o0]     = make_float4(ra[0] * nv, ra[1] * nv, ra[2] * nv, ra[3] * nv);
            *(float4*)&fa[o0 + 4] = make_float4(rb[0] * nv, rb[1] * nv, rb[2] * nv, rb[3] * nv);
        } else {
            int q0 = o0 - 192;
            *(float4*)&rpgS[q0]     = make_float4(ra[0] * nv, ra[1] * nv, ra[2] * nv, ra[3] * nv);
            *(float4*)&rpgS[q0 + 4] = make_float4(rb[0] * nv, rb[1] * nv, rb[2] * nv, rb[3] * nv);
        }
    }
    __syncthreads();
    if (t < 96) {
        int h = t >> 3, p = t & 7;
        float rv[3];
        #pragma unroll
        for (int c = 0; c < 3; ++c) rv[c] = rpgS[h * 24 + p * 3 + c] - trans[i * 3 + c];
        float l0 = rot[i * 9 + 0] * rv[0] + rot[i * 9 + 3] * rv[1] + rot[i * 9 + 6] * rv[2];
        float l1 = rot[i * 9 + 1] * rv[0] + rot[i * 9 + 4] * rv[1] + rot[i * 9 + 7] * rv[2];
        float l2 = rot[i * 9 + 2] * rv[0] + rot[i * 9 + 5] * rv[1] + rot[i * 9 + 8] * rv[2];
        float dd = sqrtf(1e-8f + l0 * l0 + l1 * l1 + l2 * l2);
        fa[192 + t] = l0;
        fa[288 + t] = l1;
        fa[384 + t] = l2;
        fa[480 + t] = dd;
    }
}

// ---------------------------------------------------------------------------
// K3: out = final_act @ w_out.T + b_out.  64x64 tiles, 4x4 micro-tile,
// 3-way split-K (K=2112=3*704) via atomicAdd into zeroed out buffer.
// Grid (12, 6, 3) = 216 blocks. Bias added by the kz==0 split.
// ---------------------------------------------------------------------------
__global__ __launch_bounds__(256) void k3_out(
    const float* __restrict__ w_out, const float* __restrict__ b_out,
    const float* __restrict__ ws, float* __restrict__ out)
{
    __shared__ __align__(16) float ASt[32][68];
    __shared__ __align__(16) float WSt[32][68];
    const int t = threadIdx.x;
    const int i0 = blockIdx.x * 64;
    const int o0 = blockIdx.y * 64;
    const int kz = blockIdx.z;
    const int kbase = kz * 704;
    const float* fa = ws + OFF_FA;
    const int tx = t & 15, ty = t >> 4;
    float acc[4][4];
    #pragma unroll
    for (int r = 0; r < 4; ++r)
        #pragma unroll
        for (int c = 0; c < 4; ++c) acc[r][c] = 0.f;

    for (int k0 = 0; k0 < 704; k0 += 32) {
        __syncthreads();
        #pragma unroll
        for (int s = 0; s < 2; ++s) {
            int q = t + 256 * s;
            int row = q >> 3, kq = (q & 7) * 4;
            float4 a4 = *(const float4*)&fa[(size_t)(i0 + row) * 2112 + kbase + k0 + kq];
            ASt[kq + 0][row] = a4.x; ASt[kq + 1][row] = a4.y;
            ASt[kq + 2][row] = a4.z; ASt[kq + 3][row] = a4.w;
            float4 w4 = *(const float4*)&w_out[(size_t)(o0 + row) * 2112 + kbase + k0 + kq];
            WSt[kq + 0][row] = w4.x; WSt[kq + 1][row] = w4.y;
            WSt[kq + 2][row] = w4.z; WSt[kq + 3][row] = w4.w;
        }
        __syncthreads();
        #pragma unroll
        for (int k = 0; k < 32; ++k) {
            float4 a4 = *(const float4*)&ASt[k][ty * 4];
            float4 w4 = *(const float4*)&WSt[k][tx * 4];
            float av[4] = {a4.x, a4.y, a4.z, a4.w};
            float wv[4] = {w4.x, w4.y, w4.z, w4.w};
            #pragma unroll
            for (int r = 0; r < 4; ++r)
                #pragma unroll
                for (int c = 0; c < 4; ++c)
                    acc[r][c] = fmaf(av[r], wv[c], acc[r][c]);
        }
    }
    float bias[4] = {0.f, 0.f, 0.f, 0.f};
    if (kz == 0) {
        #pragma unroll
        for (int c = 0; c < 4; ++c) bias[c] = b_out[o0 + tx * 4 + c];
    }
    #pragma unroll
    for (int r = 0; r < 4; ++r) {
        int oi = i0 + ty * 4 + r;
        #pragma unroll
        for (int c = 0; c < 4; ++c) {
            atomicAdd(&out[(size_t)oi * 384 + o0 + tx * 4 + c], acc[r][c] + bias[c]);
        }
    }
}

extern "C" void kernel_launch(void* const* d_in, const int* in_sizes, int n_in,
                              void* d_out, int out_size, void* d_ws, size_t ws_size,
                              hipStream_t stream) {
    const float* in1d  = (const float*)d_in[0];
    const float* in2d  = (const float*)d_in[1];
    const float* mask  = (const float*)d_in[2];
    const float* rot   = (const float*)d_in[3];
    const float* trans = (const float*)d_in[4];
    const float* w_qs  = (const float*)d_in[5];
    const float* b_qs  = (const float*)d_in[6];
    const float* w_kvs = (const float*)d_in[7];
    const float* b_kvs = (const float*)d_in[8];
    const float* w_qp  = (const float*)d_in[9];
    const float* b_qp  = (const float*)d_in[10];
    const float* w_kvp = (const float*)d_in[11];
    const float* b_kvp = (const float*)d_in[12];
    const float* tpw   = (const float*)d_in[13];
    const float* w2d   = (const float*)d_in[14];
    const float* b2d   = (const float*)d_in[15];
    const float* w_out = (const float*)d_in[16];
    const float* b_out = (const float*)d_in[17];
    float* ws  = (float*)d_ws;
    float* out = (float*)d_out;

    hipLaunchKernelGGL(k1_gemm, dim3(12, 18), dim3(256), 0, stream,
                       in1d, w_qs, b_qs, w_kvs, b_kvs, w_qp, b_qp, w_kvp, b_kvp, ws);
    hipLaunchKernelGGL(k1b_scatter, dim3(768), dim3(256), 0, stream,
                       rot, trans, ws);
    hipLaunchKernelGGL(k2_attn, dim3(768), dim3(256), 0, stream,
                       in2d, mask, rot, trans, tpw, w2d, b2d, ws);
    hipMemsetAsync(d_out, 0, out_size, stream);
    hipLaunchKernelGGL(k3_out, dim3(12, 6, 3), dim3(256), 0, stream,
                       w_out, b_out, ws, out);
}